// Round 3
// baseline (690.553 us; speedup 1.0000x reference)
//
#include <hip/hip_runtime.h>
#include <cstdint>
#include <cstddef>

#define B_ 64
#define S_ 2048
#define H_ 512
#define R_ 256
#define M_ (B_ * S_)   // 131072
#define NEGV (-1.0e9f)

typedef short short8 __attribute__((ext_vector_type(8)));
typedef unsigned short u16x8 __attribute__((ext_vector_type(8)));
typedef float f32x4 __attribute__((ext_vector_type(4)));
typedef unsigned short u16;

// ---------- helpers ----------
__device__ __forceinline__ u16 f2b(float x) {
    union { float f; uint32_t u; } c; c.f = x;
    uint32_t u = c.u;
    uint32_t r = (u + 0x7fffu + ((u >> 16) & 1u)) >> 16;   // RNE
    return (u16)r;
}
__device__ __forceinline__ float b2f(u16 u) {
    union { uint32_t u; float f; } c; c.u = ((uint32_t)u) << 16;
    return c.f;
}
__device__ __forceinline__ float fast_tanh(float v) {
    float e = __expf(2.0f * v);
    return 1.0f - 2.0f / (e + 1.0f);
}

// ---------- K0: convert sent_h to bf16 (pure stream) ----------
__global__ void k_convert(const float* __restrict__ sent, u16* __restrict__ sentb) {
    const long n8 = (long)M_ * H_ / 8;   // 8,388,608 groups of 8
    long stride = (long)gridDim.x * blockDim.x;
    for (long i = (long)blockIdx.x * blockDim.x + threadIdx.x; i < n8; i += stride) {
        float4 v0 = ((const float4*)sent)[2 * i];
        float4 v1 = ((const float4*)sent)[2 * i + 1];
        u16x8 o;
        o[0] = f2b(v0.x); o[1] = f2b(v0.y); o[2] = f2b(v0.z); o[3] = f2b(v0.w);
        o[4] = f2b(v1.x); o[5] = f2b(v1.y); o[6] = f2b(v1.z); o[7] = f2b(v1.w);
        ((u16x8*)sentb)[i] = o;
    }
}

// ---------- K1: base[b,k] (weight-stationary, grid 64) + Wh_w f32->bf16 ----------
__global__ void k_base(const float* __restrict__ rel, const float* __restrict__ pool,
                       const float* __restrict__ Wg_w, const float* __restrict__ Wg_b,
                       const float* __restrict__ Wh_b,
                       const float* __restrict__ Wr_w, const float* __restrict__ Wr_b,
                       const float* __restrict__ whw, float* __restrict__ base,
                       u16* __restrict__ whwb) {
    int q = blockIdx.x;        // 0..63, owns k-rows q*8..q*8+7, all 64 b
    int tid = threadIdx.x;
    #pragma unroll
    for (int u = 0; u < 4; ++u) {      // fold Wh_w convert: 65536 float4 over 64 blocks
        int gi = q * 1024 + u * 256 + tid;
        float4 v = ((const float4*)whw)[gi];
        ushort4 o; o.x = f2b(v.x); o.y = f2b(v.y); o.z = f2b(v.z); o.w = f2b(v.w);
        ((ushort4*)whwb)[gi] = o;
    }
    __shared__ __attribute__((aligned(16))) float swr[8 * 260];  // +4 pad: conflict-free
    __shared__ __attribute__((aligned(16))) float swg[8 * 516];
    int k0 = q * 8;
    for (int i = tid; i < 8 * 64; i += 256) {        // Wr rows: 8 x 64 float4
        int r = i >> 6, c = i & 63;
        ((float4*)(swr + r * 260))[c] = ((const float4*)(Wr_w + (size_t)(k0 + r) * R_))[c];
    }
    for (int i = tid; i < 8 * 128; i += 256) {       // Wg rows: 8 x 128 float4
        int r = i >> 7, c = i & 127;
        ((float4*)(swg + r * 516))[c] = ((const float4*)(Wg_w + (size_t)(k0 + r) * H_))[c];
    }
    __syncthreads();
    int ki = tid & 7, bi0 = tid >> 3;
    float bias = Wr_b[k0 + ki] + Wg_b[k0 + ki] + Wh_b[k0 + ki];
    #pragma unroll
    for (int p = 0; p < 2; ++p) {
        int b = bi0 + p * 32;
        float acc = bias;
        const float4* xr = (const float4*)(rel + (size_t)b * R_);
        const float4* wr = (const float4*)(swr + ki * 260);
        #pragma unroll 8
        for (int i = 0; i < 64; ++i) {
            float4 w = wr[i]; float4 x = xr[i];
            acc += w.x * x.x + w.y * x.y + w.z * x.z + w.w * x.w;
        }
        const float4* xg = (const float4*)(pool + (size_t)b * H_);
        const float4* wg = (const float4*)(swg + ki * 516);
        #pragma unroll 8
        for (int i = 0; i < 128; ++i) {
            float4 w = wg[i]; float4 x = xg[i];
            acc += w.x * x.x + w.y * x.y + w.z * x.z + w.w * x.w;
        }
        base[(size_t)b * H_ + k0 + ki] = acc;
    }
}

// ---------- K2: main GEMM, NO LDS, direct global->VGPR fragments, zero K-loop barriers ----------
__launch_bounds__(256, 2)
__global__ void k_gemm(const u16* __restrict__ A,    // [M, 512] bf16
                       const u16* __restrict__ Bw,   // [512, 512] bf16 (Wh_w)
                       const float* __restrict__ base,  // [B_, H_]
                       const float* __restrict__ alpha, // [H_]
                       float* __restrict__ partial)     // [4][M]
{
    int j = blockIdx.x;
    int xcd  = j & 7;
    int slot = j >> 3;
    int nb   = slot & 3;
    int mbg  = (slot >> 2) * 8 + xcd;   // 0..511
    int m0 = mbg * 256;
    int n0 = nb * 128;
    int b  = m0 >> 11;

    int tid = threadIdx.x;
    int w  = tid >> 6;
    int l  = tid & 63;
    int lr = l & 15;
    int lq = l >> 4;

    uint32_t aoff[4], boff[8];
    #pragma unroll
    for (int mi = 0; mi < 4; ++mi)
        aoff[mi] = (uint32_t)(m0 + w * 64 + mi * 16 + lr) * 512u + (uint32_t)(lq * 8);
    #pragma unroll
    for (int ni = 0; ni < 8; ++ni)
        boff[ni] = (uint32_t)(n0 + ni * 16 + lr) * 512u + (uint32_t)(lq * 8);

    f32x4 zero = {0.f, 0.f, 0.f, 0.f};
    f32x4 acc[4][8];
    #pragma unroll
    for (int mi = 0; mi < 4; ++mi)
        #pragma unroll
        for (int ni = 0; ni < 8; ++ni) acc[mi][ni] = zero;

    #pragma unroll
    for (int kt = 0; kt < 16; ++kt) {
        short8 av[4], bv[8];
        #pragma unroll
        for (int mi = 0; mi < 4; ++mi)
            av[mi] = *(const short8*)(A + aoff[mi] + kt * 32);
        #pragma unroll
        for (int ni = 0; ni < 8; ++ni)
            bv[ni] = *(const short8*)(Bw + boff[ni] + kt * 32);
        #pragma unroll
        for (int mi = 0; mi < 4; ++mi)
            #pragma unroll
            for (int ni = 0; ni < 8; ++ni)
                acc[mi][ni] = __builtin_amdgcn_mfma_f32_16x16x32_bf16(av[mi], bv[ni], acc[mi][ni], 0, 0, 0);
    }

    // epilogue: partial[nb][m] = sum_n tanh(C[m,n] + base[b,n]) * alpha[n]
    float basev[8], alphav[8];
    #pragma unroll
    for (int ni = 0; ni < 8; ++ni) {
        int n = n0 + ni * 16 + lr;
        basev[ni]  = base[(size_t)b * H_ + n];
        alphav[ni] = alpha[n];
    }
    #pragma unroll
    for (int mi = 0; mi < 4; ++mi) {
        #pragma unroll
        for (int r = 0; r < 4; ++r) {
            float s = 0.f;
            #pragma unroll
            for (int ni = 0; ni < 8; ++ni) {
                float v = acc[mi][ni][r] + basev[ni];
                s += fast_tanh(v) * alphav[ni];
            }
            s += __shfl_xor(s, 1);
            s += __shfl_xor(s, 2);
            s += __shfl_xor(s, 4);
            s += __shfl_xor(s, 8);
            if (lr == 0)
                partial[(size_t)nb * M_ + m0 + w * 64 + mi * 16 + lq * 4 + r] = s;
        }
    }
}

// ---------- K3: softmax over S per b ----------
__global__ void k_softmax(const float* __restrict__ partial, const int* __restrict__ mask,
                          const float* __restrict__ alpha_b, float* __restrict__ wout) {
    int b = blockIdx.x;
    int tid = threadIdx.x;
    __shared__ float sred[8];
    float x[8];
    float ab = alpha_b[0];
    float lmax = -3.0e38f;
    #pragma unroll
    for (int jj = 0; jj < 8; ++jj) {
        int s = tid + jj * 256;
        size_t m = (size_t)b * S_ + s;
        float v = partial[m] + partial[(size_t)M_ + m] + partial[2 * (size_t)M_ + m] + partial[3 * (size_t)M_ + m] + ab;
        if (mask[b * S_ + s] == 0) v = NEGV;
        x[jj] = v;
        lmax = fmaxf(lmax, v);
    }
    #pragma unroll
    for (int off = 1; off < 64; off <<= 1) lmax = fmaxf(lmax, __shfl_xor(lmax, off));
    int wv = tid >> 6, l = tid & 63;
    if (l == 0) sred[wv] = lmax;
    __syncthreads();
    float gmax = fmaxf(fmaxf(sred[0], sred[1]), fmaxf(sred[2], sred[3]));
    float lsum = 0.f;
    #pragma unroll
    for (int jj = 0; jj < 8; ++jj) { x[jj] = __expf(x[jj] - gmax); lsum += x[jj]; }
    #pragma unroll
    for (int off = 1; off < 64; off <<= 1) lsum += __shfl_xor(lsum, off);
    if (l == 0) sred[4 + wv] = lsum;
    __syncthreads();
    float inv = 1.f / (sred[4] + sred[5] + sred[6] + sred[7]);
    #pragma unroll
    for (int jj = 0; jj < 8; ++jj) {
        int s = tid + jj * 256;
        wout[(size_t)b * S_ + s] = x[jj] * inv;
    }
}

// ---------- K4: t[b,h'] = sum_s w[b,s]*sentb[b,s,h']  (grid B*4, 128 h'/block, 16B loads) ----------
__global__ void k_wsum(const u16* __restrict__ sentb, const float* __restrict__ wrow_g,
                       float* __restrict__ t) {
    int b  = blockIdx.x >> 2;
    int hc = blockIdx.x & 3;
    int tid = threadIdx.x;
    __shared__ __attribute__((aligned(16))) float wrow[S_];      // 8 KB
    __shared__ float sred[16][128];                              // 8 KB
    ((float4*)wrow)[tid]       = ((const float4*)(wrow_g + (size_t)b * S_))[tid];
    ((float4*)wrow)[tid + 256] = ((const float4*)(wrow_g + (size_t)b * S_))[tid + 256];
    __syncthreads();
    int hi = tid & 15, sg = tid >> 4;   // 16 lanes span 128 h' (8 each), 16 s-groups
    const u16* bp = sentb + (size_t)b * S_ * H_ + hc * 128 + hi * 8;
    float a[8];
    #pragma unroll
    for (int jj = 0; jj < 8; ++jj) a[jj] = 0.f;
    for (int si = 0; si < S_; si += 128) {
        #pragma unroll
        for (int u = 0; u < 8; ++u) {       // 8 independent 16B loads in flight
            int s = si + sg + u * 16;
            u16x8 v = *(const u16x8*)(bp + (size_t)s * H_);
            float wgt = wrow[s];
            #pragma unroll
            for (int jj = 0; jj < 8; ++jj) a[jj] += wgt * b2f(v[jj]);
        }
    }
    #pragma unroll
    for (int jj = 0; jj < 8; ++jj) sred[sg][hi * 8 + jj] = a[jj];
    __syncthreads();
    if (tid < 128) {
        float s = 0.f;
        #pragma unroll
        for (int g = 0; g < 16; ++g) s += sred[g][tid];
        t[(size_t)b * H_ + hc * 128 + tid] = s;
    }
}

// ---------- K5: att_res (weight-stationary, grid 64) ----------
__global__ void k_att(const float* __restrict__ t, const float* __restrict__ Whw,
                      const float* __restrict__ Whb, float* __restrict__ out) {
    int q = blockIdx.x;        // owns k-rows q*8..q*8+7, all 64 b
    int tid = threadIdx.x;
    __shared__ __attribute__((aligned(16))) float sw[8 * 516];
    int k0 = q * 8;
    for (int i = tid; i < 8 * 128; i += 256) {
        int r = i >> 7, c = i & 127;
        ((float4*)(sw + r * 516))[c] = ((const float4*)(Whw + (size_t)(k0 + r) * H_))[c];
    }
    __syncthreads();
    int ki = tid & 7, bi0 = tid >> 3;
    float bias = Whb[k0 + ki];
    #pragma unroll
    for (int p = 0; p < 2; ++p) {
        int b = bi0 + p * 32;
        float acc = bias;
        const float4* xv = (const float4*)(t + (size_t)b * H_);
        const float4* wv = (const float4*)(sw + ki * 516);
        #pragma unroll 8
        for (int i = 0; i < 128; ++i) {
            float4 w = wv[i]; float4 x = xv[i];
            acc += w.x * x.x + w.y * x.y + w.z * x.z + w.w * x.w;
        }
        out[(size_t)b * H_ + k0 + ki] = acc;
    }
}

extern "C" void kernel_launch(void* const* d_in, const int* in_sizes, int n_in,
                              void* d_out, int out_size, void* d_ws, size_t ws_size,
                              hipStream_t stream) {
    const float* sent_h  = (const float*)d_in[0];
    const float* rel     = (const float*)d_in[1];
    const float* pool    = (const float*)d_in[2];
    const int*   mask    = (const int*)d_in[3];
    const float* Wg_w    = (const float*)d_in[4];
    const float* Wg_b    = (const float*)d_in[5];
    const float* Wh_w    = (const float*)d_in[6];
    const float* Wh_b    = (const float*)d_in[7];
    const float* Wr_w    = (const float*)d_in[8];
    const float* Wr_b    = (const float*)d_in[9];
    const float* alpha_w = (const float*)d_in[10];
    const float* alpha_b = (const float*)d_in[11];
    float* out = (float*)d_out;

    char* ws = (char*)d_ws;
    u16*   sentb   = (u16*)ws;                                   // 134217728 B
    u16*   whwb    = (u16*)(ws + 134217728);                     // 524288 B
    float* base    = (float*)(ws + 134217728 + 524288);          // 131072 B
    float* partial = (float*)(ws + 134217728 + 524288 + 131072); // 2097152 B
    float* tbuf    = (float*)(ws + 134217728 + 524288 + 131072 + 2097152); // 131072 B

    float* att_out = out;             // [64,512]
    float* w_out   = out + B_ * H_;   // [64,2048]

    k_convert<<<dim3(8192), dim3(256), 0, stream>>>(sent_h, sentb);
    k_base<<<dim3(64), dim3(256), 0, stream>>>(rel, pool, Wg_w, Wg_b, Wh_b, Wr_w, Wr_b, Wh_w, base, whwb);
    k_gemm<<<dim3(2048), dim3(256), 0, stream>>>(sentb, whwb, base, alpha_w, partial);
    k_softmax<<<dim3(B_), dim3(256), 0, stream>>>(partial, mask, alpha_b, w_out);
    k_wsum<<<dim3(B_ * 4), dim3(256), 0, stream>>>(sentb, w_out, tbuf);
    k_att<<<dim3(64), dim3(256), 0, stream>>>(tbuf, Wh_w, Wh_b, att_out);
}